// Round 1
// baseline (17733.965 us; speedup 1.0000x reference)
//
#include <hip/hip_runtime.h>
#include <cstdint>
#include <cstddef>

// ---------------------------------------------------------------------------
// RNN seq2seq: emb gather -> 4x (xz GEMM + 128-step LSTM scan) -> dense.
// All matmuls in split-bf16 (hi/lo) MFMA, 3 MFMAs per logical product:
//   a*b ~= ah*bh + ah*bl + al*bh   (rel err ~2^-16, fp32-class)
// ---------------------------------------------------------------------------

#define H_    1024
#define G4H   4096
#define B_    32
#define T_    128
#define BT_   4096
#define V_    32000

typedef unsigned short u16;
typedef __attribute__((ext_vector_type(8))) short   short8;
typedef __attribute__((ext_vector_type(8))) __bf16  bf16x8;
typedef __attribute__((ext_vector_type(4))) float   f32x4;

__device__ __forceinline__ u16 f2bf(float f) {
  unsigned u = __float_as_uint(f);
  u += 0x7fffu + ((u >> 16) & 1u);
  return (u16)(u >> 16);
}
__device__ __forceinline__ float bf2f(u16 s) {
  return __uint_as_float(((unsigned)s) << 16);
}
__device__ __forceinline__ f32x4 MF(short8 a, short8 b, f32x4 c) {
  return __builtin_amdgcn_mfma_f32_16x16x32_bf16(
      __builtin_bit_cast(bf16x8, a), __builtin_bit_cast(bf16x8, b), c, 0, 0, 0);
}
// async global->LDS, 16B per lane; LDS dest is wave-uniform base + lane*16
__device__ __forceinline__ void g2lds16(const void* g, void* l) {
  __builtin_amdgcn_global_load_lds(
      (const __attribute__((address_space(1))) unsigned int*)g,
      (__attribute__((address_space(3))) unsigned int*)l, 16, 0, 0);
}

// ---------------------------------------------------------------------------
// grid barrier (non-cooperative; all 256 blocks provably co-resident)
// ---------------------------------------------------------------------------
__device__ __forceinline__ void gbar(unsigned* cnt, unsigned* gen) {
  __syncthreads();
  if (threadIdx.x == 0) {
    __threadfence();  // release: drain + wb to coherent point
    unsigned g = __hip_atomic_load(gen, __ATOMIC_RELAXED, __HIP_MEMORY_SCOPE_AGENT);
    unsigned a = __hip_atomic_fetch_add(cnt, 1u, __ATOMIC_ACQ_REL, __HIP_MEMORY_SCOPE_AGENT);
    if (a == gridDim.x - 1) {
      __hip_atomic_store(cnt, 0u, __ATOMIC_RELAXED, __HIP_MEMORY_SCOPE_AGENT);
      __hip_atomic_fetch_add(gen, 1u, __ATOMIC_RELEASE, __HIP_MEMORY_SCOPE_AGENT);
    } else {
      while (__hip_atomic_load(gen, __ATOMIC_ACQUIRE, __HIP_MEMORY_SCOPE_AGENT) == g)
        __builtin_amdgcn_s_sleep(2);
    }
    __threadfence();  // acquire: invalidate stale L1/L2
  }
  __syncthreads();
}

// ---------------------------------------------------------------------------
// embedding gather -> packed-A layout [mb=b][kap][r=t][e] (bf16 hi/lo)
// value A[row=b*128+t][k=8*kap+e]
// ---------------------------------------------------------------------------
__global__ __launch_bounds__(256) void k_embed(
    const int* __restrict__ etok, const int* __restrict__ dtok,
    const float* __restrict__ emb,
    u16* __restrict__ xh, u16* __restrict__ xl,
    u16* __restrict__ yh, u16* __restrict__ yl) {
  int tid  = blockIdx.x * 256 + threadIdx.x;  // 2 * 4096 * 128
  int half = tid >> 19;
  int loc  = tid & 524287;
  int row  = loc >> 7;
  int kap  = loc & 127;
  int tok  = half ? dtok[row] : etok[row];
  const float* src = emb + (size_t)tok * H_ + kap * 8;
  u16* dh = half ? yh : xh;
  u16* dl = half ? yl : xl;
  int b = row >> 7, t = row & 127;
  size_t off = ((size_t)(b * 128 + kap) * 128 + t) * 8;
  unsigned hi[4], lo[4];
#pragma unroll
  for (int p = 0; p < 4; ++p) {
    float v0 = src[2 * p], v1 = src[2 * p + 1];
    u16 h0 = f2bf(v0), h1 = f2bf(v1);
    u16 l0 = f2bf(v0 - bf2f(h0)), l1 = f2bf(v1 - bf2f(h1));
    hi[p] = (unsigned)h0 | ((unsigned)h1 << 16);
    lo[p] = (unsigned)l0 | ((unsigned)l1 << 16);
  }
  *(uint4*)(dh + off) = make_uint4(hi[0], hi[1], hi[2], hi[3]);
  *(uint4*)(dl + off) = make_uint4(lo[0], lo[1], lo[2], lo[3]);
}

// ---------------------------------------------------------------------------
// W[k][n] fp32 -> packed-B [nb][kap][c][e] bf16 hi/lo
// ---------------------------------------------------------------------------
__global__ __launch_bounds__(256) void k_convW(
    const float* __restrict__ W, u16* __restrict__ bh, u16* __restrict__ bl) {
  int tid = blockIdx.x * 256 + threadIdx.x;  // 32*128*128
  int c = tid & 127, kap = (tid >> 7) & 127, nb = tid >> 14;
  int n = nb * 128 + c;
  unsigned hi[4], lo[4];
#pragma unroll
  for (int p = 0; p < 4; ++p) {
    float v0 = W[(size_t)(8 * kap + 2 * p) * G4H + n];
    float v1 = W[(size_t)(8 * kap + 2 * p + 1) * G4H + n];
    u16 h0 = f2bf(v0), h1 = f2bf(v1);
    u16 l0 = f2bf(v0 - bf2f(h0)), l1 = f2bf(v1 - bf2f(h1));
    hi[p] = (unsigned)h0 | ((unsigned)h1 << 16);
    lo[p] = (unsigned)l0 | ((unsigned)l1 << 16);
  }
  size_t off = ((size_t)(nb * 128 + kap) * 128 + c) * 8;
  *(uint4*)(bh + off) = make_uint4(hi[0], hi[1], hi[2], hi[3]);
  *(uint4*)(bl + off) = make_uint4(lo[0], lo[1], lo[2], lo[3]);
}

// ---------------------------------------------------------------------------
// U[k][n] fp32 -> Upack [col][kap][e] bf16 hi/lo (for scan LDS staging)
// ---------------------------------------------------------------------------
__global__ __launch_bounds__(256) void k_convU(
    const float* __restrict__ U, u16* __restrict__ uh, u16* __restrict__ ul) {
  int tid = blockIdx.x * 256 + threadIdx.x;  // 4096*128
  int col = tid & 4095, kap = tid >> 12;
  unsigned hi[4], lo[4];
#pragma unroll
  for (int p = 0; p < 4; ++p) {
    float v0 = U[(size_t)(8 * kap + 2 * p) * G4H + col];
    float v1 = U[(size_t)(8 * kap + 2 * p + 1) * G4H + col];
    u16 h0 = f2bf(v0), h1 = f2bf(v1);
    u16 l0 = f2bf(v0 - bf2f(h0)), l1 = f2bf(v1 - bf2f(h1));
    hi[p] = (unsigned)h0 | ((unsigned)h1 << 16);
    lo[p] = (unsigned)l0 | ((unsigned)l1 << 16);
  }
  size_t off = ((size_t)col * 128 + kap) * 8;
  *(uint4*)(uh + off) = make_uint4(hi[0], hi[1], hi[2], hi[3]);
  *(uint4*)(ul + off) = make_uint4(lo[0], lo[1], lo[2], lo[3]);
}

// ---------------------------------------------------------------------------
// xz = A @ W + bias.  A: packed-A hi/lo, W: packed-B hi/lo, C fp32 [4096][4096]
// 128x128 tile, BK=32, 4 waves (2x2), global_load_lds staging, 3-term split.
// ---------------------------------------------------------------------------
__global__ __launch_bounds__(256) void k_gemm(
    const u16* __restrict__ Ah, const u16* __restrict__ Al,
    const u16* __restrict__ Bh, const u16* __restrict__ Bl,
    const float* __restrict__ bias, float* __restrict__ C) {
  __shared__ u16 lds[16384];  // Ah | Al | Bh | Bl, 4096 shorts each
  int bm = blockIdx.x >> 5, bn = blockIdx.x & 31;
  int tid = threadIdx.x, lane = tid & 63, wv = tid >> 6;
  int wm = wv >> 1, wn = wv & 1;
  int kl = lane >> 4, rr = lane & 15;
  const f32x4 fz = {0.f, 0.f, 0.f, 0.f};
  f32x4 acc[4][4];
#pragma unroll
  for (int i = 0; i < 4; ++i)
#pragma unroll
    for (int j = 0; j < 4; ++j) acc[i][j] = fz;

  const u16* sbase = (wv == 0) ? Ah : (wv == 1) ? Al : (wv == 2) ? Bh : Bl;
  int blkidx = (wv < 2) ? bm : bn;
  u16* ldst = &lds[wv * 4096];

  for (int kt = 0; kt < 32; ++kt) {
    __syncthreads();
    const u16* src = sbase + ((size_t)(blkidx * 128 + kt * 4) * 128) * 8;
#pragma unroll
    for (int i = 0; i < 8; ++i)
      g2lds16(src + i * 512 + lane * 8, ldst + i * 512);
    asm volatile("s_waitcnt vmcnt(0)" ::: "memory");
    __syncthreads();

    short8 af[2][4], bf[2][4];
#pragma unroll
    for (int mi = 0; mi < 4; ++mi) {
      int o = (kl * 128 + wm * 64 + mi * 16 + rr) * 8;
      af[0][mi] = *(const short8*)&lds[o];
      af[1][mi] = *(const short8*)&lds[4096 + o];
    }
#pragma unroll
    for (int ni = 0; ni < 4; ++ni) {
      int o = (kl * 128 + wn * 64 + ni * 16 + rr) * 8;
      bf[0][ni] = *(const short8*)&lds[8192 + o];
      bf[1][ni] = *(const short8*)&lds[12288 + o];
    }
#pragma unroll
    for (int mi = 0; mi < 4; ++mi)
#pragma unroll
      for (int ni = 0; ni < 4; ++ni) {
        acc[mi][ni] = MF(af[0][mi], bf[0][ni], acc[mi][ni]);
        acc[mi][ni] = MF(af[0][mi], bf[1][ni], acc[mi][ni]);
        acc[mi][ni] = MF(af[1][mi], bf[0][ni], acc[mi][ni]);
      }
  }
  // epilogue: D lane layout col=lane&15, row=(lane>>4)*4+j
#pragma unroll
  for (int ni = 0; ni < 4; ++ni) {
    int col = bn * 128 + wn * 64 + ni * 16 + rr;
    float bv = bias[col];
#pragma unroll
    for (int mi = 0; mi < 4; ++mi) {
      int row0 = bm * 128 + wm * 64 + mi * 16 + kl * 4;
#pragma unroll
      for (int j = 0; j < 4; ++j)
        C[(size_t)(row0 + j) * G4H + col] = acc[mi][ni][j] + bv;
    }
  }
}

// ---------------------------------------------------------------------------
// persistent LSTM scan: 256 blocks x 128 threads (2 waves: m=0/1).
// Block G owns hidden units 4G..4G+3 (16 gate cols, LDS col c = q*4+uu).
// U hi/lo in 64KB LDS; h broadcast via packed global [kap][b][e] double buffer.
// One grid barrier per timestep. Gates per-lane via 3 shuffles.
// ---------------------------------------------------------------------------
__global__ __launch_bounds__(128) void k_scan(
    const u16* __restrict__ Uph, const u16* __restrict__ Upl,
    const float* __restrict__ xz,
    u16* __restrict__ h0h, u16* __restrict__ h0l,
    u16* __restrict__ h1h, u16* __restrict__ h1l,
    float* __restrict__ hf32, float* __restrict__ cstate,
    u16* __restrict__ hsH, u16* __restrict__ hsL,
    unsigned* cnt, unsigned* gen) {
  __shared__ u16 Us[32768];  // [buf][kap 128][c 16][e 8]
  const int G = blockIdx.x;
  const int tid = threadIdx.x;
  const int lane = tid & 63;
  const int m = tid >> 6;           // wave: batch half
  const int kl = lane >> 4;
  const int c = lane & 15;
  const int q = c >> 2;             // gate: 0=i 1=f 2=g 3=o
  const int uuc = c & 3;            // unit within block
  const int u = 4 * G + uuc;
  const int kap_u = u >> 3;
  const int e_u = u & 7;
  const int bb0 = m * 16 + c;       // A-frag row for this lane

  // stage U pair into LDS (wave m stages buffer m)
#pragma unroll
  for (int i = 0; i < 32; ++i) {
    int kb = i * 4;
    int kapl = kb + kl;
    int coll = q * H_ + 4 * G + uuc;
    const u16* gsrc = (m ? Upl : Uph) + ((size_t)coll * 128 + kapl) * 8;
    g2lds16(gsrc, &Us[m * 16384 + kb * 128]);
  }
  asm volatile("s_waitcnt vmcnt(0)" ::: "memory");
  __syncthreads();

  // carry state (meaningful on q0 lanes)
  float cst[4];
#pragma unroll
  for (int j = 0; j < 4; ++j)
    cst[j] = cstate[(size_t)(m * 16 + 4 * kl + j) * H_ + u];

  const f32x4 fz = {0.f, 0.f, 0.f, 0.f};
#pragma unroll 1
  for (int t = 0; t < T_; ++t) {
    const int rb = t & 1;
    const u16* hh = rb ? h1h : h0h;
    const u16* hl = rb ? h1l : h0l;
    u16* whh = rb ? h0h : h1h;
    u16* whl = rb ? h0l : h1l;

    float xzv[4];
#pragma unroll
    for (int j = 0; j < 4; ++j) {
      int bb = m * 16 + 4 * kl + j;
      xzv[j] = xz[(size_t)(bb * 128 + t) * G4H + q * H_ + 4 * G + uuc];
    }

    f32x4 av[4] = {fz, fz, fz, fz};
#pragma unroll
    for (int ks = 0; ks < 32; ++ks) {
      int kap = ks * 4 + kl;
      short8 ah = *(const short8*)&hh[((size_t)kap * 32 + bb0) * 8];
      short8 al = *(const short8*)&hl[((size_t)kap * 32 + bb0) * 8];
      short8 bh = *(const short8*)&Us[kap * 128 + c * 8];
      short8 bl = *(const short8*)&Us[16384 + kap * 128 + c * 8];
      av[ks & 3] = MF(ah, bh, av[ks & 3]);
      av[ks & 3] = MF(ah, bl, av[ks & 3]);
      av[ks & 3] = MF(al, bh, av[ks & 3]);
    }
    f32x4 zs = av[0] + av[1] + av[2] + av[3];

    float nl[4];
#pragma unroll
    for (int j = 0; j < 4; ++j) {
      float z = zs[j] + xzv[j];
      float s = (q == 2) ? 2.f * z : z;
      float sg = 1.f / (1.f + __expf(-s));
      nl[j] = (q == 2) ? (2.f * sg - 1.f) : sg;   // tanh via sigmoid
    }
    int base = lane & 48;
    int lf = base | (4 + uuc), lg_ = base | (8 + uuc), lo_ = base | (12 + uuc);
#pragma unroll
    for (int j = 0; j < 4; ++j) {
      float fv = __shfl(nl[j], lf, 64);
      float gv = __shfl(nl[j], lg_, 64);
      float ov = __shfl(nl[j], lo_, 64);
      if (c < 4) {  // q0 lanes own (b,u) state
        float cn = fv * cst[j] + nl[j] * gv;
        cst[j] = cn;
        float e2 = __expf(-2.f * cn);
        float hv = ov * ((1.f - e2) / (1.f + e2));
        int bb = m * 16 + 4 * kl + j;
        u16 hb = f2bf(hv);
        u16 lb = f2bf(hv - bf2f(hb));
        whh[((size_t)kap_u * 32 + bb) * 8 + e_u] = hb;
        whl[((size_t)kap_u * 32 + bb) * 8 + e_u] = lb;
        hf32[(size_t)bb * H_ + u] = hv;
        if (hsH != nullptr) {
          size_t ho = ((size_t)(bb * 128 + kap_u) * 128 + t) * 8 + e_u;
          hsH[ho] = hb;
          hsL[ho] = lb;
        }
      }
    }
    if (t != T_ - 1) gbar(cnt, gen);
  }
  if (c < 4) {
#pragma unroll
    for (int j = 0; j < 4; ++j)
      cstate[(size_t)(m * 16 + 4 * kl + j) * H_ + u] = cst[j];
  }
}

// ---------------------------------------------------------------------------
// out[b][v] = h[b][:] . Wd[:][v] + bd[v]   (fp32 vector, memory-bound)
// ---------------------------------------------------------------------------
__global__ __launch_bounds__(256) void k_dense(
    const float* __restrict__ hf, const float* __restrict__ Wd,
    const float* __restrict__ bd, float* __restrict__ out) {
  __shared__ float hs_l[32][64];
  int tid = threadIdx.x;
  int v = blockIdx.x * 256 + tid;
  float acc[32];
#pragma unroll
  for (int b = 0; b < 32; ++b) acc[b] = 0.f;
  for (int kc = 0; kc < 16; ++kc) {
    __syncthreads();
    {
      int b = tid >> 3, k0 = (tid & 7) * 8;
      const float* s = &hf[(size_t)b * H_ + kc * 64 + k0];
      *(float4*)&hs_l[b][k0] = *(const float4*)s;
      *(float4*)&hs_l[b][k0 + 4] = *(const float4*)(s + 4);
    }
    __syncthreads();
#pragma unroll 4
    for (int k4 = 0; k4 < 16; ++k4) {
      float w0 = Wd[(size_t)(kc * 64 + k4 * 4 + 0) * V_ + v];
      float w1 = Wd[(size_t)(kc * 64 + k4 * 4 + 1) * V_ + v];
      float w2 = Wd[(size_t)(kc * 64 + k4 * 4 + 2) * V_ + v];
      float w3 = Wd[(size_t)(kc * 64 + k4 * 4 + 3) * V_ + v];
#pragma unroll
      for (int b = 0; b < 32; ++b) {
        float4 hv = *(const float4*)&hs_l[b][k4 * 4];
        acc[b] += hv.x * w0 + hv.y * w1 + hv.z * w2 + hv.w * w3;
      }
    }
  }
#pragma unroll
  for (int b = 0; b < 32; ++b)
    out[(size_t)b * V_ + v] = acc[b] + bd[v];
}

// ---------------------------------------------------------------------------
// host side
// ---------------------------------------------------------------------------
static const size_t OFF_CNT = 0;
static const size_t OFF_GEN = 64;
static const size_t OFF_CST = 256;                      // 32*1024*4
static const size_t OFF_H0H = OFF_CST + 131072;
static const size_t OFF_H0L = OFF_H0H + 65536;
static const size_t INIT_BYTES = OFF_H0L + 65536;       // zeroed each launch
static const size_t OFF_H1H = INIT_BYTES;
static const size_t OFF_H1L = OFF_H1H + 65536;
static const size_t OFF_HF  = OFF_H1L + 65536;
static const size_t OFF_XZ  = OFF_HF + 131072;          // 4096*4096*4
static const size_t OFF_XEH = OFF_XZ + 67108864;
static const size_t OFF_XEL = OFF_XEH + 8388608;
static const size_t OFF_YDH = OFF_XEL + 8388608;
static const size_t OFF_YDL = OFF_YDH + 8388608;
static const size_t OFF_HSH = OFF_YDL + 8388608;
static const size_t OFF_HSL = OFF_HSH + 8388608;
static const size_t OFF_WPH = OFF_HSL + 8388608;
static const size_t OFF_WPL = OFF_WPH + 8388608;
static const size_t OFF_UPH = OFF_WPL + 8388608;
static const size_t OFF_UPL = OFF_UPH + 8388608;
static const size_t WS_NEED = OFF_UPL + 8388608;        // ~144.5 MB

extern "C" void kernel_launch(void* const* d_in, const int* in_sizes, int n_in,
                              void* d_out, int out_size, void* d_ws, size_t ws_size,
                              hipStream_t stream) {
  if (ws_size < WS_NEED) return;  // workspace too small: fail visibly
  const int*   etok = (const int*)d_in[0];
  const int*   dtok = (const int*)d_in[1];
  const float* emb  = (const float*)d_in[2];
  const float* encW = (const float*)d_in[3];
  const float* encU = (const float*)d_in[4];
  const float* encB = (const float*)d_in[5];
  const float* decW = (const float*)d_in[6];
  const float* decU = (const float*)d_in[7];
  const float* decB = (const float*)d_in[8];
  const float* dW   = (const float*)d_in[9];
  const float* dB   = (const float*)d_in[10];
  float* out = (float*)d_out;
  char* ws = (char*)d_ws;

  unsigned* cnt = (unsigned*)(ws + OFF_CNT);
  unsigned* gen = (unsigned*)(ws + OFF_GEN);
  float* cstate = (float*)(ws + OFF_CST);
  u16* h0h = (u16*)(ws + OFF_H0H);
  u16* h0l = (u16*)(ws + OFF_H0L);
  u16* h1h = (u16*)(ws + OFF_H1H);
  u16* h1l = (u16*)(ws + OFF_H1L);
  float* hf32 = (float*)(ws + OFF_HF);
  float* xz   = (float*)(ws + OFF_XZ);
  u16* xEh = (u16*)(ws + OFF_XEH);
  u16* xEl = (u16*)(ws + OFF_XEL);
  u16* yDh = (u16*)(ws + OFF_YDH);
  u16* yDl = (u16*)(ws + OFF_YDL);
  u16* hsH = (u16*)(ws + OFF_HSH);
  u16* hsL = (u16*)(ws + OFF_HSL);
  u16* Wph = (u16*)(ws + OFF_WPH);
  u16* Wpl = (u16*)(ws + OFF_WPL);
  u16* Uph = (u16*)(ws + OFF_UPH);
  u16* Upl = (u16*)(ws + OFF_UPL);

  // zero: barrier state, c0, h0 (packed buf0 pair)
  hipMemsetAsync(ws, 0, INIT_BYTES, stream);

  k_embed<<<4096, 256, 0, stream>>>(etok, dtok, emb, xEh, xEl, yDh, yDl);

  for (int l = 0; l < 4; ++l) {
    const float* Wsrc = (l < 2) ? encW + (size_t)l * H_ * G4H : decW + (size_t)(l - 2) * H_ * G4H;
    const float* Usrc = (l < 2) ? encU + (size_t)l * H_ * G4H : decU + (size_t)(l - 2) * H_ * G4H;
    const float* bsrc = (l < 2) ? encB + (size_t)l * G4H      : decB + (size_t)(l - 2) * G4H;
    const u16* Ah = (l == 0) ? xEh : (l == 2) ? yDh : hsH;
    const u16* Al = (l == 0) ? xEl : (l == 2) ? yDl : hsL;
    bool emit = (l == 0 || l == 2);  // layers 1,3: hs unused downstream

    k_convW<<<2048, 256, 0, stream>>>(Wsrc, Wph, Wpl);
    k_gemm<<<1024, 256, 0, stream>>>(Ah, Al, Wph, Wpl, bsrc, xz);
    k_convU<<<2048, 256, 0, stream>>>(Usrc, Uph, Upl);
    k_scan<<<256, 128, 0, stream>>>(Uph, Upl, xz, h0h, h0l, h1h, h1l, hf32, cstate,
                                    emit ? hsH : nullptr, emit ? hsL : nullptr,
                                    cnt, gen);
  }
  k_dense<<<125, 256, 0, stream>>>(hf32, dW, dB, out);
}

// Round 2
// 15111.679 us; speedup vs baseline: 1.1735x; 1.1735x over previous
//
#include <hip/hip_runtime.h>
#include <cstdint>
#include <cstddef>

// ---------------------------------------------------------------------------
// RNN seq2seq: emb gather -> 4x (xz GEMM + 128-step LSTM scan) -> dense.
// All matmuls in split-bf16 (hi/lo) MFMA, 3 MFMAs per logical product:
//   a*b ~= ah*bh + ah*bl + al*bh   (rel err ~2^-16, fp32-class)
// R1 -> R2: flag-array grid barrier with RELAXED polls (no per-poll L2 inv),
//           xz transposed to [t][col][b] (float4 scan reads), hf32 last-step.
// ---------------------------------------------------------------------------

#define H_    1024
#define G4H   4096
#define B_    32
#define T_    128
#define BT_   4096
#define V_    32000

typedef unsigned short u16;
typedef __attribute__((ext_vector_type(8))) short   short8;
typedef __attribute__((ext_vector_type(8))) __bf16  bf16x8;
typedef __attribute__((ext_vector_type(4))) float   f32x4;

__device__ __forceinline__ u16 f2bf(float f) {
  unsigned u = __float_as_uint(f);
  u += 0x7fffu + ((u >> 16) & 1u);
  return (u16)(u >> 16);
}
__device__ __forceinline__ float bf2f(u16 s) {
  return __uint_as_float(((unsigned)s) << 16);
}
__device__ __forceinline__ f32x4 MF(short8 a, short8 b, f32x4 c) {
  return __builtin_amdgcn_mfma_f32_16x16x32_bf16(
      __builtin_bit_cast(bf16x8, a), __builtin_bit_cast(bf16x8, b), c, 0, 0, 0);
}
// async global->LDS, 16B per lane; LDS dest is wave-uniform base + lane*16
__device__ __forceinline__ void g2lds16(const void* g, void* l) {
  __builtin_amdgcn_global_load_lds(
      (const __attribute__((address_space(1))) unsigned int*)g,
      (__attribute__((address_space(3))) unsigned int*)l, 16, 0, 0);
}

// ---------------------------------------------------------------------------
// grid barrier v2: per-block arrive flags + relaxed polling.
// Release store (one L2 wb) -> relaxed agent polls (LLC reads, NO inv) ->
// one seq_cst fence on exit (one inv). 256 blocks x 128 threads.
// ---------------------------------------------------------------------------
__device__ __forceinline__ void gbarf(unsigned* flags, unsigned stepval) {
  __syncthreads();  // both waves' stores drained (vmcnt0) before flag store
  if (threadIdx.x == 0)
    __hip_atomic_store(&flags[blockIdx.x], stepval, __ATOMIC_RELEASE,
                       __HIP_MEMORY_SCOPE_AGENT);
  unsigned* f = flags + 2 * threadIdx.x;  // 128 thr x 2 = 256 flags
  for (;;) {
    unsigned a = __hip_atomic_load(&f[0], __ATOMIC_RELAXED, __HIP_MEMORY_SCOPE_AGENT);
    unsigned b = __hip_atomic_load(&f[1], __ATOMIC_RELAXED, __HIP_MEMORY_SCOPE_AGENT);
    if (__all((a >= stepval) & (b >= stepval))) break;
    __builtin_amdgcn_s_sleep(1);
  }
  __threadfence();  // acquire side: invalidate stale L1/L2 once
  __syncthreads();
}

// ---------------------------------------------------------------------------
// embedding gather -> packed-A layout [mb=b][kap][r=t][e] (bf16 hi/lo)
// value A[row=b*128+t][k=8*kap+e]
// ---------------------------------------------------------------------------
__global__ __launch_bounds__(256) void k_embed(
    const int* __restrict__ etok, const int* __restrict__ dtok,
    const float* __restrict__ emb,
    u16* __restrict__ xh, u16* __restrict__ xl,
    u16* __restrict__ yh, u16* __restrict__ yl) {
  int tid  = blockIdx.x * 256 + threadIdx.x;  // 2 * 4096 * 128
  int half = tid >> 19;
  int loc  = tid & 524287;
  int row  = loc >> 7;
  int kap  = loc & 127;
  int tok  = half ? dtok[row] : etok[row];
  const float* src = emb + (size_t)tok * H_ + kap * 8;
  u16* dh = half ? yh : xh;
  u16* dl = half ? yl : xl;
  int b = row >> 7, t = row & 127;
  size_t off = ((size_t)(b * 128 + kap) * 128 + t) * 8;
  unsigned hi[4], lo[4];
#pragma unroll
  for (int p = 0; p < 4; ++p) {
    float v0 = src[2 * p], v1 = src[2 * p + 1];
    u16 h0 = f2bf(v0), h1 = f2bf(v1);
    u16 l0 = f2bf(v0 - bf2f(h0)), l1 = f2bf(v1 - bf2f(h1));
    hi[p] = (unsigned)h0 | ((unsigned)h1 << 16);
    lo[p] = (unsigned)l0 | ((unsigned)l1 << 16);
  }
  *(uint4*)(dh + off) = make_uint4(hi[0], hi[1], hi[2], hi[3]);
  *(uint4*)(dl + off) = make_uint4(lo[0], lo[1], lo[2], lo[3]);
}

// ---------------------------------------------------------------------------
// W[k][n] fp32 -> packed-B [nb][kap][c][e] bf16 hi/lo
// ---------------------------------------------------------------------------
__global__ __launch_bounds__(256) void k_convW(
    const float* __restrict__ W, u16* __restrict__ bh, u16* __restrict__ bl) {
  int tid = blockIdx.x * 256 + threadIdx.x;  // 32*128*128
  int c = tid & 127, kap = (tid >> 7) & 127, nb = tid >> 14;
  int n = nb * 128 + c;
  unsigned hi[4], lo[4];
#pragma unroll
  for (int p = 0; p < 4; ++p) {
    float v0 = W[(size_t)(8 * kap + 2 * p) * G4H + n];
    float v1 = W[(size_t)(8 * kap + 2 * p + 1) * G4H + n];
    u16 h0 = f2bf(v0), h1 = f2bf(v1);
    u16 l0 = f2bf(v0 - bf2f(h0)), l1 = f2bf(v1 - bf2f(h1));
    hi[p] = (unsigned)h0 | ((unsigned)h1 << 16);
    lo[p] = (unsigned)l0 | ((unsigned)l1 << 16);
  }
  size_t off = ((size_t)(nb * 128 + kap) * 128 + c) * 8;
  *(uint4*)(bh + off) = make_uint4(hi[0], hi[1], hi[2], hi[3]);
  *(uint4*)(bl + off) = make_uint4(lo[0], lo[1], lo[2], lo[3]);
}

// ---------------------------------------------------------------------------
// U[k][n] fp32 -> Upack [col][kap][e] bf16 hi/lo (for scan LDS staging)
// ---------------------------------------------------------------------------
__global__ __launch_bounds__(256) void k_convU(
    const float* __restrict__ U, u16* __restrict__ uh, u16* __restrict__ ul) {
  int tid = blockIdx.x * 256 + threadIdx.x;  // 4096*128
  int col = tid & 4095, kap = tid >> 12;
  unsigned hi[4], lo[4];
#pragma unroll
  for (int p = 0; p < 4; ++p) {
    float v0 = U[(size_t)(8 * kap + 2 * p) * G4H + col];
    float v1 = U[(size_t)(8 * kap + 2 * p + 1) * G4H + col];
    u16 h0 = f2bf(v0), h1 = f2bf(v1);
    u16 l0 = f2bf(v0 - bf2f(h0)), l1 = f2bf(v1 - bf2f(h1));
    hi[p] = (unsigned)h0 | ((unsigned)h1 << 16);
    lo[p] = (unsigned)l0 | ((unsigned)l1 << 16);
  }
  size_t off = ((size_t)col * 128 + kap) * 8;
  *(uint4*)(uh + off) = make_uint4(hi[0], hi[1], hi[2], hi[3]);
  *(uint4*)(ul + off) = make_uint4(lo[0], lo[1], lo[2], lo[3]);
}

// ---------------------------------------------------------------------------
// xzT[t][col][b] = (A @ W + bias).  A: packed-A hi/lo, W: packed-B hi/lo.
// 128x128 tile, BK=32, 4 waves (2x2), global_load_lds staging, 3-term split.
// ---------------------------------------------------------------------------
__global__ __launch_bounds__(256) void k_gemm(
    const u16* __restrict__ Ah, const u16* __restrict__ Al,
    const u16* __restrict__ Bh, const u16* __restrict__ Bl,
    const float* __restrict__ bias, float* __restrict__ xzT) {
  __shared__ u16 lds[16384];  // Ah | Al | Bh | Bl, 4096 shorts each
  int bm = blockIdx.x >> 5, bn = blockIdx.x & 31;
  int tid = threadIdx.x, lane = tid & 63, wv = tid >> 6;
  int wm = wv >> 1, wn = wv & 1;
  int kl = lane >> 4, rr = lane & 15;
  const f32x4 fz = {0.f, 0.f, 0.f, 0.f};
  f32x4 acc[4][4];
#pragma unroll
  for (int i = 0; i < 4; ++i)
#pragma unroll
    for (int j = 0; j < 4; ++j) acc[i][j] = fz;

  const u16* sbase = (wv == 0) ? Ah : (wv == 1) ? Al : (wv == 2) ? Bh : Bl;
  int blkidx = (wv < 2) ? bm : bn;
  u16* ldst = &lds[wv * 4096];

  for (int kt = 0; kt < 32; ++kt) {
    __syncthreads();
    const u16* src = sbase + ((size_t)(blkidx * 128 + kt * 4) * 128) * 8;
#pragma unroll
    for (int i = 0; i < 8; ++i)
      g2lds16(src + i * 512 + lane * 8, ldst + i * 512);
    asm volatile("s_waitcnt vmcnt(0)" ::: "memory");
    __syncthreads();

    short8 af[2][4], bf[2][4];
#pragma unroll
    for (int mi = 0; mi < 4; ++mi) {
      int o = (kl * 128 + wm * 64 + mi * 16 + rr) * 8;
      af[0][mi] = *(const short8*)&lds[o];
      af[1][mi] = *(const short8*)&lds[4096 + o];
    }
#pragma unroll
    for (int ni = 0; ni < 4; ++ni) {
      int o = (kl * 128 + wn * 64 + ni * 16 + rr) * 8;
      bf[0][ni] = *(const short8*)&lds[8192 + o];
      bf[1][ni] = *(const short8*)&lds[12288 + o];
    }
#pragma unroll
    for (int mi = 0; mi < 4; ++mi)
#pragma unroll
      for (int ni = 0; ni < 4; ++ni) {
        acc[mi][ni] = MF(af[0][mi], bf[0][ni], acc[mi][ni]);
        acc[mi][ni] = MF(af[0][mi], bf[1][ni], acc[mi][ni]);
        acc[mi][ni] = MF(af[1][mi], bf[0][ni], acc[mi][ni]);
      }
  }
  // epilogue: D lane layout col=lane&15, row=(lane>>4)*4+j; row = b*128 + t
#pragma unroll
  for (int ni = 0; ni < 4; ++ni) {
    int col = bn * 128 + wn * 64 + ni * 16 + rr;
    float bv = bias[col];
#pragma unroll
    for (int mi = 0; mi < 4; ++mi) {
      int row0 = bm * 128 + wm * 64 + mi * 16 + kl * 4;
#pragma unroll
      for (int j = 0; j < 4; ++j) {
        int row = row0 + j;
        int bb = row >> 7, tt = row & 127;
        xzT[((size_t)tt * G4H + col) * 32 + bb] = acc[mi][ni][j] + bv;
      }
    }
  }
}

// ---------------------------------------------------------------------------
// persistent LSTM scan: 256 blocks x 128 threads (2 waves: m=0/1).
// Block G owns hidden units 4G..4G+3 (16 gate cols, LDS col c = q*4+uu).
// U hi/lo in 64KB LDS; h broadcast via packed global [kap][b][e] double buffer.
// One flag-barrier per timestep. Gates per-lane via 3 shuffles.
// ---------------------------------------------------------------------------
__global__ __launch_bounds__(128) void k_scan(
    const u16* __restrict__ Uph, const u16* __restrict__ Upl,
    const float* __restrict__ xzT,
    u16* __restrict__ h0h, u16* __restrict__ h0l,
    u16* __restrict__ h1h, u16* __restrict__ h1l,
    float* __restrict__ hf32, float* __restrict__ cstate,
    u16* __restrict__ hsH, u16* __restrict__ hsL,
    unsigned* flags, unsigned sbase) {
  __shared__ u16 Us[32768];  // [buf][kap 128][c 16][e 8]
  const int G = blockIdx.x;
  const int tid = threadIdx.x;
  const int lane = tid & 63;
  const int m = tid >> 6;           // wave: batch half
  const int kl = lane >> 4;
  const int c = lane & 15;
  const int q = c >> 2;             // gate: 0=i 1=f 2=g 3=o
  const int uuc = c & 3;            // unit within block
  const int u = 4 * G + uuc;
  const int kap_u = u >> 3;
  const int e_u = u & 7;
  const int bb0 = m * 16 + c;       // A-frag row for this lane
  const bool emit = (hsH != nullptr);

  // stage U pair into LDS (wave m stages buffer m)
#pragma unroll
  for (int i = 0; i < 32; ++i) {
    int kb = i * 4;
    int kapl = kb + kl;
    int coll = q * H_ + 4 * G + uuc;
    const u16* gsrc = (m ? Upl : Uph) + ((size_t)coll * 128 + kapl) * 8;
    g2lds16(gsrc, &Us[m * 16384 + kb * 128]);
  }
  asm volatile("s_waitcnt vmcnt(0)" ::: "memory");
  __syncthreads();

  // carry state (meaningful on q0 lanes)
  float cst[4];
#pragma unroll
  for (int j = 0; j < 4; ++j)
    cst[j] = cstate[(size_t)(m * 16 + 4 * kl + j) * H_ + u];

  const f32x4 fz = {0.f, 0.f, 0.f, 0.f};
#pragma unroll 1
  for (int t = 0; t < T_; ++t) {
    const int rb = t & 1;
    const u16* hh = rb ? h1h : h0h;
    const u16* hl = rb ? h1l : h0l;
    u16* whh = rb ? h0h : h1h;
    u16* whl = rb ? h0l : h1l;

    // xz read: [t][col][b], 4 consecutive b per lane -> one float4
    const float4 xv = *(const float4*)&xzT[
        ((size_t)t * G4H + q * H_ + 4 * G + uuc) * 32 + m * 16 + 4 * kl];

    f32x4 av[4] = {fz, fz, fz, fz};
#pragma unroll
    for (int ks = 0; ks < 32; ++ks) {
      int kap = ks * 4 + kl;
      short8 ah = *(const short8*)&hh[((size_t)kap * 32 + bb0) * 8];
      short8 al = *(const short8*)&hl[((size_t)kap * 32 + bb0) * 8];
      short8 bh = *(const short8*)&Us[kap * 128 + c * 8];
      short8 bl = *(const short8*)&Us[16384 + kap * 128 + c * 8];
      av[ks & 3] = MF(ah, bh, av[ks & 3]);
      av[ks & 3] = MF(ah, bl, av[ks & 3]);
      av[ks & 3] = MF(al, bh, av[ks & 3]);
    }
    f32x4 zs = av[0] + av[1] + av[2] + av[3];

    float nl[4];
    const float xzv[4] = {xv.x, xv.y, xv.z, xv.w};
#pragma unroll
    for (int j = 0; j < 4; ++j) {
      float z = zs[j] + xzv[j];
      float s = (q == 2) ? 2.f * z : z;
      float sg = 1.f / (1.f + __expf(-s));
      nl[j] = (q == 2) ? (2.f * sg - 1.f) : sg;   // tanh via sigmoid
    }
    int base = lane & 48;
    int lf = base | (4 + uuc), lg_ = base | (8 + uuc), lo_ = base | (12 + uuc);
#pragma unroll
    for (int j = 0; j < 4; ++j) {
      float fv = __shfl(nl[j], lf, 64);
      float gv = __shfl(nl[j], lg_, 64);
      float ov = __shfl(nl[j], lo_, 64);
      if (c < 4) {  // q0 lanes own (b,u) state
        float cn = fv * cst[j] + nl[j] * gv;
        cst[j] = cn;
        float e2 = __expf(-2.f * cn);
        float hv = ov * ((1.f - e2) / (1.f + e2));
        int bb = m * 16 + 4 * kl + j;
        u16 hb = f2bf(hv);
        u16 lb = f2bf(hv - bf2f(hb));
        whh[((size_t)kap_u * 32 + bb) * 8 + e_u] = hb;
        whl[((size_t)kap_u * 32 + bb) * 8 + e_u] = lb;
        if (t == T_ - 1) hf32[(size_t)bb * H_ + u] = hv;
        if (emit) {
          size_t ho = ((size_t)(bb * 128 + kap_u) * 128 + t) * 8 + e_u;
          hsH[ho] = hb;
          hsL[ho] = lb;
        }
      }
    }
    if (t != T_ - 1) gbarf(flags, sbase + t + 1);
  }
  if (c < 4) {
#pragma unroll
    for (int j = 0; j < 4; ++j)
      cstate[(size_t)(m * 16 + 4 * kl + j) * H_ + u] = cst[j];
  }
}

// ---------------------------------------------------------------------------
// out[b][v] = h[b][:] . Wd[:][v] + bd[v]   (fp32 vector, memory-bound)
// ---------------------------------------------------------------------------
__global__ __launch_bounds__(256) void k_dense(
    const float* __restrict__ hf, const float* __restrict__ Wd,
    const float* __restrict__ bd, float* __restrict__ out) {
  __shared__ float hs_l[32][64];
  int tid = threadIdx.x;
  int v = blockIdx.x * 256 + tid;
  float acc[32];
#pragma unroll
  for (int b = 0; b < 32; ++b) acc[b] = 0.f;
  for (int kc = 0; kc < 16; ++kc) {
    __syncthreads();
    {
      int b = tid >> 3, k0 = (tid & 7) * 8;
      const float* s = &hf[(size_t)b * H_ + kc * 64 + k0];
      *(float4*)&hs_l[b][k0] = *(const float4*)s;
      *(float4*)&hs_l[b][k0 + 4] = *(const float4*)(s + 4);
    }
    __syncthreads();
#pragma unroll 4
    for (int k4 = 0; k4 < 16; ++k4) {
      float w0 = Wd[(size_t)(kc * 64 + k4 * 4 + 0) * V_ + v];
      float w1 = Wd[(size_t)(kc * 64 + k4 * 4 + 1) * V_ + v];
      float w2 = Wd[(size_t)(kc * 64 + k4 * 4 + 2) * V_ + v];
      float w3 = Wd[(size_t)(kc * 64 + k4 * 4 + 3) * V_ + v];
#pragma unroll
      for (int b = 0; b < 32; ++b) {
        float4 hv = *(const float4*)&hs_l[b][k4 * 4];
        acc[b] += hv.x * w0 + hv.y * w1 + hv.z * w2 + hv.w * w3;
      }
    }
  }
#pragma unroll
  for (int b = 0; b < 32; ++b)
    out[(size_t)b * V_ + v] = acc[b] + bd[v];
}

// ---------------------------------------------------------------------------
// host side
// ---------------------------------------------------------------------------
static const size_t OFF_FLG = 0;                        // 256 * 4 = 1 KB
static const size_t OFF_CST = 1024;                     // 32*1024*4
static const size_t OFF_H0H = OFF_CST + 131072;
static const size_t OFF_H0L = OFF_H0H + 65536;
static const size_t INIT_BYTES = OFF_H0L + 65536;       // zeroed each launch
static const size_t OFF_H1H = INIT_BYTES;
static const size_t OFF_H1L = OFF_H1H + 65536;
static const size_t OFF_HF  = OFF_H1L + 65536;
static const size_t OFF_XZ  = OFF_HF + 131072;          // 4096*4096*4 (xzT)
static const size_t OFF_XEH = OFF_XZ + 67108864;
static const size_t OFF_XEL = OFF_XEH + 8388608;
static const size_t OFF_YDH = OFF_XEL + 8388608;
static const size_t OFF_YDL = OFF_YDH + 8388608;
static const size_t OFF_HSH = OFF_YDL + 8388608;
static const size_t OFF_HSL = OFF_HSH + 8388608;
static const size_t OFF_WPH = OFF_HSL + 8388608;
static const size_t OFF_WPL = OFF_WPH + 8388608;
static const size_t OFF_UPH = OFF_WPL + 8388608;
static const size_t OFF_UPL = OFF_UPH + 8388608;
static const size_t WS_NEED = OFF_UPL + 8388608;        // ~144.5 MB

extern "C" void kernel_launch(void* const* d_in, const int* in_sizes, int n_in,
                              void* d_out, int out_size, void* d_ws, size_t ws_size,
                              hipStream_t stream) {
  if (ws_size < WS_NEED) return;  // workspace too small: fail visibly
  const int*   etok = (const int*)d_in[0];
  const int*   dtok = (const int*)d_in[1];
  const float* emb  = (const float*)d_in[2];
  const float* encW = (const float*)d_in[3];
  const float* encU = (const float*)d_in[4];
  const float* encB = (const float*)d_in[5];
  const float* decW = (const float*)d_in[6];
  const float* decU = (const float*)d_in[7];
  const float* decB = (const float*)d_in[8];
  const float* dW   = (const float*)d_in[9];
  const float* dB   = (const float*)d_in[10];
  float* out = (float*)d_out;
  char* ws = (char*)d_ws;

  unsigned* flags = (unsigned*)(ws + OFF_FLG);
  float* cstate = (float*)(ws + OFF_CST);
  u16* h0h = (u16*)(ws + OFF_H0H);
  u16* h0l = (u16*)(ws + OFF_H0L);
  u16* h1h = (u16*)(ws + OFF_H1H);
  u16* h1l = (u16*)(ws + OFF_H1L);
  float* hf32 = (float*)(ws + OFF_HF);
  float* xzT  = (float*)(ws + OFF_XZ);
  u16* xEh = (u16*)(ws + OFF_XEH);
  u16* xEl = (u16*)(ws + OFF_XEL);
  u16* yDh = (u16*)(ws + OFF_YDH);
  u16* yDl = (u16*)(ws + OFF_YDL);
  u16* hsH = (u16*)(ws + OFF_HSH);
  u16* hsL = (u16*)(ws + OFF_HSL);
  u16* Wph = (u16*)(ws + OFF_WPH);
  u16* Wpl = (u16*)(ws + OFF_WPL);
  u16* Uph = (u16*)(ws + OFF_UPH);
  u16* Upl = (u16*)(ws + OFF_UPL);

  // zero: barrier flags, c0, h0 (packed buf0 pair)
  hipMemsetAsync(ws, 0, INIT_BYTES, stream);

  k_embed<<<4096, 256, 0, stream>>>(etok, dtok, emb, xEh, xEl, yDh, yDl);

  for (int l = 0; l < 4; ++l) {
    const float* Wsrc = (l < 2) ? encW + (size_t)l * H_ * G4H : decW + (size_t)(l - 2) * H_ * G4H;
    const float* Usrc = (l < 2) ? encU + (size_t)l * H_ * G4H : decU + (size_t)(l - 2) * H_ * G4H;
    const float* bsrc = (l < 2) ? encB + (size_t)l * G4H      : decB + (size_t)(l - 2) * G4H;
    const u16* Ah = (l == 0) ? xEh : (l == 2) ? yDh : hsH;
    const u16* Al = (l == 0) ? xEl : (l == 2) ? yDl : hsL;
    bool emit = (l == 0 || l == 2);  // layers 1,3: hs unused downstream

    k_convW<<<2048, 256, 0, stream>>>(Wsrc, Wph, Wpl);
    k_gemm<<<1024, 256, 0, stream>>>(Ah, Al, Wph, Wpl, bsrc, xzT);
    k_convU<<<2048, 256, 0, stream>>>(Usrc, Uph, Upl);
    k_scan<<<256, 128, 0, stream>>>(Uph, Upl, xzT, h0h, h0l, h1h, h1l, hf32, cstate,
                                    emit ? hsH : nullptr, emit ? hsL : nullptr,
                                    flags, (unsigned)(l * 128));
  }
  k_dense<<<125, 256, 0, stream>>>(hf32, dW, dB, out);
}